// Round 1
// 1144.328 us; speedup vs baseline: 1.1113x; 1.1113x over previous
//
#include <hip/hip_runtime.h>
#include <hip/hip_bf16.h>
#include <stdint.h>

static constexpr int N_NODES = 100000;
static constexpr int N_EDGES = 1600000;
static constexpr int PAD_ROWS = 100096;   // 782 * 128, removes GEMM A-tile bounds checks

// bucketed CSR build: 64 rows per bucket
static constexpr int BKT_SHIFT = 6;
static constexpr int RPB = 1 << BKT_SHIFT;            // 64 rows / bucket
static constexpr int NB_BKT = PAD_ROWS >> BKT_SHIFT;  // 1564 buckets
static constexpr int BCAP = 1280;                     // mean 1023, sd 32 -> +8 sigma

typedef _Float16 f16;
using f16x8 = __attribute__((ext_vector_type(8))) _Float16;
using f16x4v = __attribute__((ext_vector_type(4))) _Float16;
using f32x4 = __attribute__((ext_vector_type(4))) float;

__device__ __forceinline__ void gld_lds16(const void* g, void* l) {
  __builtin_amdgcn_global_load_lds((const __attribute__((address_space(1))) void*)g,
                                   (__attribute__((address_space(3))) void*)l, 16, 0, 0);
}

// piecewise multi-term ReLU activation: 1.8*soft(0.1) - 0.8*soft(0.5)
__device__ __forceinline__ float custom_act(float x) {
  float s1 = fmaxf(x - 0.1f, 0.f) - fmaxf(-x - 0.1f, 0.f);
  float s2 = fmaxf(x - 0.5f, 0.f) - fmaxf(-x - 0.5f, 0.f);
  return 1.8f * s1 - 0.8f * s2;
}

// ---------------- conversions ----------------
__global__ __launch_bounds__(256) void xconv_k(const float* __restrict__ src, f16* __restrict__ dst, int n4) {
  int i = blockIdx.x * 256 + threadIdx.x;
  if (i < n4) {
    float4 v = ((const float4*)src)[i];
    f16x4v h = {(f16)v.x, (f16)v.y, (f16)v.z, (f16)v.w};
    ((f16x4v*)dst)[i] = h;
  }
}
// fp32 [K][N] -> f16 [N][K]
__global__ __launch_bounds__(256) void wconv_k(const float* __restrict__ src, f16* __restrict__ dst, int K, int N) {
  int i = blockIdx.x * 256 + threadIdx.x;
  if (i < K * N) { int k = i / N, n = i - k * N; dst[n * K + k] = (f16)src[i]; }
}

// ---------------- bucketed CSR build ----------------
// phase 1: append (packed rowlocal|col, val) records to per-bucket regions.
// Bucket writes fill sequentially -> lines coalesce in L2/LLC (no 8x write blowup).
__global__ __launch_bounds__(256) void bucket_k(const int* __restrict__ Ai, const float* __restrict__ Av,
                                                int* __restrict__ bcA, int2* __restrict__ bufA,
                                                const int* __restrict__ Li, const float* __restrict__ Lv,
                                                int* __restrict__ bcL, int2* __restrict__ bufL, int E) {
  int e = blockIdx.x * 256 + threadIdx.x;
  if (e >= E) return;
  {
    int r = Ai[e], c = Ai[E + e];
    int b = r >> BKT_SHIFT;
    int p = atomicAdd(&bcA[b * 16], 1);   // counters padded to 64B to avoid same-line atomic pileup
    if (p < BCAP) bufA[(size_t)b * BCAP + p] = make_int2(((r & (RPB - 1)) << 17) | c, __float_as_int(Av[e]));
  }
  {
    int r = Li[e], c = Li[E + e];
    int b = r >> BKT_SHIFT;
    int p = atomicAdd(&bcL[b * 16], 1);
    if (p < BCAP) bufL[(size_t)b * BCAP + p] = make_int2(((r & (RPB - 1)) << 17) | c, __float_as_int(Lv[e]));
  }
}

// scan bucket totals (strided counters) -> bucket base offsets
__global__ __launch_bounds__(1024) void scan_k(const int* __restrict__ cntA, int* __restrict__ rpA,
                                               const int* __restrict__ cntL, int* __restrict__ rpL,
                                               int n, int stride) {
  const int* cnt = blockIdx.x ? cntL : cntA;
  int* rp = blockIdx.x ? rpL : rpA;
  __shared__ int wsum[16];
  __shared__ int carry_s;
  int tid = threadIdx.x, lane = tid & 63, wv = tid >> 6;
  if (tid == 0) carry_s = 0;
  __syncthreads();
  for (int base = 0; base < n; base += 1024) {
    int i = base + tid;
    int v = (i < n) ? cnt[i * stride] : 0;
    int s = v;
    #pragma unroll
    for (int off = 1; off < 64; off <<= 1) {
      int t = __shfl_up(s, off, 64);
      if (lane >= off) s += t;
    }
    if (lane == 63) wsum[wv] = s;
    __syncthreads();
    if (wv == 0 && lane < 16) {
      int w = wsum[lane];
      #pragma unroll
      for (int off = 1; off < 16; off <<= 1) {
        int t = __shfl_up(w, off, 64);
        if (lane >= off) w += t;
      }
      wsum[lane] = w;
    }
    __syncthreads();
    int carry = carry_s;
    int woff = wv ? wsum[wv - 1] : 0;
    if (i < n) rp[i] = carry + woff + s - v;
    __syncthreads();
    if (tid == 1023) carry_s = carry + woff + s;
    __syncthreads();
  }
  if (tid == 0) rp[n] = carry_s;
}

// phase 2: per bucket -- stage records in LDS, count per-row, scan 64 counters,
// write rp slice coalesced, place records into the bucket's contiguous rec window.
__global__ __launch_bounds__(256) void place_k(const int* __restrict__ bcA, const int* __restrict__ bbA,
                                               const int2* __restrict__ bufA, int* __restrict__ rpA,
                                               int2* __restrict__ recA,
                                               const int* __restrict__ bcL, const int* __restrict__ bbL,
                                               const int2* __restrict__ bufL, int* __restrict__ rpL,
                                               int2* __restrict__ recL) {
  const int b = blockIdx.x;
  const int* bc; const int* bb; const int2* buf; int* rp; int2* rec;
  if (blockIdx.y) { bc = bcL; bb = bbL; buf = bufL; rp = rpL; rec = recL; }
  else            { bc = bcA; bb = bbA; buf = bufA; rp = rpA; rec = recA; }
  __shared__ int2 lrec[BCAP];
  __shared__ int lcur[RPB];
  int tid = threadIdx.x;
  int nrec = min(bc[b * 16], BCAP);
  for (int i = tid; i < nrec; i += 256) lrec[i] = buf[(size_t)b * BCAP + i];
  if (tid < RPB) lcur[tid] = 0;
  __syncthreads();
  for (int i = tid; i < nrec; i += 256) atomicAdd(&lcur[lrec[i].x >> 17], 1);
  __syncthreads();
  if (tid < 64) {
    int c = lcur[tid];
    int incl = c;
    #pragma unroll
    for (int off = 1; off < 64; off <<= 1) {
      int t = __shfl_up(incl, off, 64);
      if (tid >= off) incl += t;
    }
    int base = bb[b] + incl - c;      // exclusive prefix + global bucket base
    rp[b * RPB + tid] = base;
    lcur[tid] = base;                 // becomes global cursor
  }
  __syncthreads();
  for (int i = tid; i < nrec; i += 256) {
    int2 r = lrec[i];
    int pos = atomicAdd(&lcur[r.x >> 17], 1);
    rec[pos] = make_int2(r.x & 0x1FFFF, r.y);
  }
}

// ---------------- gather SpMM over f16 features, fp32 accumulate ----------------
// mode 0: out = relu(acc + bias);  mode 1: out = custom_act(base - acc) (in-place ok)
template<int VEC>
__global__ __launch_bounds__(256) void spmm_k(const int* __restrict__ rp, const int2* __restrict__ rec,
                                              const f16* __restrict__ X,
                                              const f16* __restrict__ base, const float* __restrict__ bias,
                                              f16* __restrict__ out, int mode, int nrows) {
  int lane = threadIdx.x & 63;
  int row = blockIdx.x * 4 + (threadIdx.x >> 6);
  if (row >= nrows) return;
  const int M = VEC * 64;
  int p0 = rp[row], p1 = rp[row + 1];
  float acc[VEC] = {};
  int p = p0;
  for (; p + 1 < p1; p += 2) {
    int2 e0 = rec[p], e1 = rec[p + 1];
    float v0 = __int_as_float(e0.y), v1 = __int_as_float(e1.y);
    if (VEC == 4) {
      f16x4v x0 = *(const f16x4v*)(X + (size_t)e0.x * M + lane * 4);
      f16x4v x1 = *(const f16x4v*)(X + (size_t)e1.x * M + lane * 4);
      #pragma unroll
      for (int j = 0; j < 4; ++j) acc[j] += v0 * (float)x0[j] + v1 * (float)x1[j];
    } else {
      float x0 = (float)X[(size_t)e0.x * M + lane];
      float x1 = (float)X[(size_t)e1.x * M + lane];
      acc[0] += v0 * x0 + v1 * x1;
    }
  }
  if (p < p1) {
    int2 e0 = rec[p];
    float v0 = __int_as_float(e0.y);
    if (VEC == 4) {
      f16x4v x0 = *(const f16x4v*)(X + (size_t)e0.x * M + lane * 4);
      #pragma unroll
      for (int j = 0; j < 4; ++j) acc[j] += v0 * (float)x0[j];
    } else {
      acc[0] += v0 * (float)X[(size_t)e0.x * M + lane];
    }
  }
  size_t o = (size_t)row * M + (size_t)lane * VEC;
  if (VEC == 4) {
    f16x4v r;
    if (mode == 0) {
      #pragma unroll
      for (int j = 0; j < 4; ++j) r[j] = (f16)fmaxf(acc[j] + bias[lane * 4 + j], 0.f);
    } else {
      f16x4v bv = *(const f16x4v*)(base + o);
      #pragma unroll
      for (int j = 0; j < 4; ++j) r[j] = (f16)custom_act((float)bv[j] - acc[j]);
    }
    *(f16x4v*)(out + o) = r;
  } else {
    if (mode == 0) out[o] = (f16)fmaxf(acc[0] + bias[lane], 0.f);
    else out[o] = (f16)custom_act((float)base[o] - acc[0]);
  }
}

// ---------------- f16 MFMA GEMM with global_load_lds staging ----------------
// C = epi(A1@B1 [+ A2@B2] + bias). A row-major (PAD_ROWS rows allocated, no load
// bounds checks); Bt pre-transposed f16 [N][K]; tile 128 x BN, BK=32,
// 4 waves x 32 rows, mfma_f32_16x16x32_f16 (layouts as verified in round 4).
template<int BN>
__global__ __launch_bounds__(256) void gemm_k(const f16* __restrict__ A1, int K1,
                                              const f16* __restrict__ A2, int K2,
                                              const f16* __restrict__ B1t, const f16* __restrict__ B2t,
                                              const float* __restrict__ bias,
                                              void* __restrict__ C, int cf16, int epi,
                                              int nrows, int ldc) {
  __shared__ f16 As[128 * 32];
  __shared__ f16 Bs[BN * 32];
  int tid = threadIdx.x, lane = tid & 63, wv = tid >> 6;
  int m16 = lane & 15, quad = lane >> 4;
  int r0 = blockIdx.x * 128, c0 = blockIdx.y * BN;
  int wr0 = wv * 32;
  f32x4 acc[2][BN / 16] = {};
  // staging geometry: lane l stages row base+(l>>2), granule l&3 -> lds base + 16B*l
  int srow = lane >> 2, scol = (lane & 3) * 8;
  for (int src = 0; src < 2; ++src) {
    const f16* A = src ? A2 : A1;
    if (!A) continue;
    int K = src ? K2 : K1;
    const f16* Bt = src ? B2t : B1t;
    const f16* gA = A + (size_t)(r0 + wr0 + srow) * K + scol;
    const f16* gB = (BN == 128) ? Bt + (size_t)(c0 + wr0 + srow) * K + scol
                                : Bt + (size_t)(c0 + wv * 16 + srow) * K + scol;
    f16* lA = &As[wr0 * 32];
    f16* lB = (BN == 128) ? &Bs[wr0 * 32] : &Bs[wv * 16 * 32];
    for (int k0 = 0; k0 < K; k0 += 32) {
      gld_lds16(gA + k0, lA);
      gld_lds16(gA + k0 + (size_t)16 * K, lA + 512);
      gld_lds16(gB + k0, lB);
      if (BN == 128) gld_lds16(gB + k0 + (size_t)16 * K, lB + 512);
      __syncthreads();
      f16x8 a0 = *(const f16x8*)&As[(wr0 + m16) * 32 + quad * 8];
      f16x8 a1 = *(const f16x8*)&As[(wr0 + 16 + m16) * 32 + quad * 8];
      #pragma unroll
      for (int bt = 0; bt < BN / 16; ++bt) {
        f16x8 b = *(const f16x8*)&Bs[(bt * 16 + m16) * 32 + quad * 8];
        acc[0][bt] = __builtin_amdgcn_mfma_f32_16x16x32_f16(a0, b, acc[0][bt], 0, 0, 0);
        acc[1][bt] = __builtin_amdgcn_mfma_f32_16x16x32_f16(a1, b, acc[1][bt], 0, 0, 0);
      }
      __syncthreads();
    }
  }
  #pragma unroll
  for (int rt = 0; rt < 2; ++rt) {
    #pragma unroll
    for (int bt = 0; bt < BN / 16; ++bt) {
      #pragma unroll
      for (int j = 0; j < 4; ++j) {
        int row = r0 + wr0 + rt * 16 + quad * 4 + j;
        if (row >= nrows) continue;
        int colp = c0 + bt * 16 + m16;
        float v = acc[rt][bt][j];
        if (bias) v += bias[colp];
        if (epi == 1) v = tanhf(v);
        size_t o = (size_t)row * ldc + colp;
        if (cf16) ((f16*)C)[o] = (f16)v;
        else ((float*)C)[o] = v;
      }
    }
  }
}

extern "C" void kernel_launch(void* const* d_in, const int* in_sizes, int n_in,
                              void* d_out, int out_size, void* d_ws, size_t ws_size,
                              hipStream_t stream) {
  const float* x  = (const float*)d_in[0];
  const int*   Ai = (const int*)d_in[1];
  const float* Av = (const float*)d_in[2];
  const int*   Li = (const int*)d_in[3];
  const float* Lv = (const float*)d_in[4];
  const float* gcn_w0 = (const float*)d_in[5];
  const float* gcn_b0 = (const float*)d_in[6];
  const float* pai1_0 = (const float*)d_in[7];
  const float* pai2_0 = (const float*)d_in[8];
  const float* w1_w0  = (const float*)d_in[9];
  const float* w1_b0  = (const float*)d_in[10];
  const float* w2_w0  = (const float*)d_in[11];
  const float* w2_b0  = (const float*)d_in[12];
  const float* gcn_w1 = (const float*)d_in[13];
  const float* gcn_b1 = (const float*)d_in[14];
  const float* pai1_1 = (const float*)d_in[15];
  const float* pai2_1 = (const float*)d_in[16];
  const float* w1_w1  = (const float*)d_in[17];
  const float* w1_b1  = (const float*)d_in[18];
  const float* w2_w1  = (const float*)d_in[19];
  const float* w2_b1  = (const float*)d_in[20];
  float* out = (float*)d_out;

  const int N = N_NODES, E = N_EDGES;
  const size_t PH = (size_t)PAD_ROWS * 256;   // padded f16 elems per 256-wide matrix
  const size_t Pd = (size_t)PAD_ROWS * 64;
  const size_t Nd = (size_t)N * 64;

  // ---- workspace carve ----
  f16* xh  = (f16*)d_ws;               // PH
  f16* R1  = xh + PH;                  // PH
  f16* R2  = R1 + PH;                  // PH
  f16* wts = R2 + PH;                  // 274432 f16 weight pool
  f16* gcn_w0t = wts;
  f16* pai1_0t = gcn_w0t + 65536;
  f16* pai2_0t = pai1_0t + 65536;
  f16* w1_w0t  = pai2_0t + 65536;
  f16* w2_w0t  = w1_w0t + 16384;
  f16* gcn_w1t = w2_w0t + 16384;
  f16* pai2_1t = gcn_w1t + 16384;
  f16* pai1_1t = pai2_1t + 16384;
  f16* w1_w1t  = pai1_1t + 4096;
  f16* w2_w1t  = w1_w1t + 4096;
  int2* recA = (int2*)(((uintptr_t)(w2_w1t + 4096) + 255) & ~(uintptr_t)255);  // E
  int2* recL = recA + E;                                                        // E
  int*  rpA  = (int*)(recL + E);       // PAD_ROWS (rows 100000..100095 hold E)
  int*  rpL  = rpA + PAD_ROWS;         // PAD_ROWS
  int*  bcA  = rpL + PAD_ROWS;         // NB_BKT*16 (padded counters)
  int*  bcL  = bcA + NB_BKT * 16;      // NB_BKT*16
  int*  bbA  = bcL + NB_BKT * 16;      // NB_BKT+1
  int*  bbL  = bbA + (NB_BKT + 1);     // NB_BKT+1

  // bucket buffers alias R1 (stream-ordered: CSR build completes before first GEMM writes R1)
  int2* bufA = (int2*)R1;                       // NB_BKT*BCAP records (16 MB)
  int2* bufL = bufA + (size_t)NB_BKT * BCAP;    // NB_BKT*BCAP records (16 MB)

  // layer-1 sub-buffers inside R2 (ldc=64, padded rows)
  f16* T1h   = R2;
  f16* Ztp1h = R2 + Pd;
  f16* Z1bh  = R2 + 2 * Pd;

  // ---- conversions + CSR build ----
  xconv_k<<<(int)(((size_t)N * 64 + 255) / 256), 256, 0, stream>>>(x, xh, N * 64);
  wconv_k<<<(65536 + 255) / 256, 256, 0, stream>>>(gcn_w0, gcn_w0t, 256, 256);
  wconv_k<<<(65536 + 255) / 256, 256, 0, stream>>>(pai1_0, pai1_0t, 256, 256);
  wconv_k<<<(65536 + 255) / 256, 256, 0, stream>>>(pai2_0, pai2_0t, 256, 256);
  wconv_k<<<(16384 + 255) / 256, 256, 0, stream>>>(w1_w0, w1_w0t, 256, 64);
  wconv_k<<<(16384 + 255) / 256, 256, 0, stream>>>(w2_w0, w2_w0t, 256, 64);
  wconv_k<<<(16384 + 255) / 256, 256, 0, stream>>>(gcn_w1, gcn_w1t, 256, 64);
  wconv_k<<<(16384 + 255) / 256, 256, 0, stream>>>(pai2_1, pai2_1t, 256, 64);
  wconv_k<<<(4096 + 255) / 256, 256, 0, stream>>>(pai1_1, pai1_1t, 64, 64);
  wconv_k<<<(4096 + 255) / 256, 256, 0, stream>>>(w1_w1, w1_w1t, 64, 64);
  wconv_k<<<(4096 + 255) / 256, 256, 0, stream>>>(w2_w1, w2_w1t, 64, 64);

  hipMemsetAsync(bcA, 0, sizeof(int) * (size_t)NB_BKT * 16 * 2, stream);
  bucket_k<<<(E + 255) / 256, 256, 0, stream>>>(Ai, Av, bcA, bufA, Li, Lv, bcL, bufL, E);
  scan_k<<<2, 1024, 0, stream>>>(bcA, bbA, bcL, bbL, NB_BKT, 16);
  place_k<<<dim3(NB_BKT, 2), 256, 0, stream>>>(bcA, bbA, bufA, rpA, recA,
                                               bcL, bbL, bufL, rpL, recL);

  const int MB = PAD_ROWS / 128;  // 782
  dim3 g256(MB, 2), g64(MB, 1);
  const int spmm_grid = (N + 3) / 4;

  // ---- layer 0 ----
  gemm_k<128><<<g256, 256, 0, stream>>>(xh, 256, nullptr, 0, gcn_w0t, nullptr, nullptr, R1, 1, 0, N, 256);
  spmm_k<4><<<spmm_grid, 256, 0, stream>>>(rpA, recA, R1, nullptr, gcn_b0, R2, 0, N);
  gemm_k<64><<<g64, 256, 0, stream>>>(R2, 256, nullptr, 0, w1_w0t, nullptr, w1_b0, out, 0, 1, N, 64);
  gemm_k<128><<<g256, 256, 0, stream>>>(R2, 256, xh, 256, pai1_0t, pai2_0t, nullptr, R1, 1, 0, N, 256);
  spmm_k<4><<<spmm_grid, 256, 0, stream>>>(rpL, recL, R2, R1, nullptr, R1, 1, N);
  gemm_k<64><<<g64, 256, 0, stream>>>(R1, 256, nullptr, 0, w2_w0t, nullptr, w2_b0, out + 2 * Nd, 0, 1, N, 64);

  // ---- layer 1 ----
  gemm_k<64><<<g64, 256, 0, stream>>>(R1, 256, nullptr, 0, gcn_w1t, nullptr, nullptr, T1h, 1, 0, N, 64);
  spmm_k<1><<<spmm_grid, 256, 0, stream>>>(rpA, recA, T1h, nullptr, gcn_b1, Ztp1h, 0, N);
  gemm_k<64><<<g64, 256, 0, stream>>>(Ztp1h, 64, nullptr, 0, w1_w1t, nullptr, w1_b1, out + Nd, 0, 1, N, 64);
  gemm_k<64><<<g64, 256, 0, stream>>>(Ztp1h, 64, xh, 256, pai1_1t, pai2_1t, nullptr, Z1bh, 1, 0, N, 64);
  spmm_k<1><<<spmm_grid, 256, 0, stream>>>(rpL, recL, Ztp1h, Z1bh, nullptr, Z1bh, 1, N);
  gemm_k<64><<<g64, 256, 0, stream>>>(Z1bh, 64, nullptr, 0, w2_w1t, nullptr, w2_b1, out + 3 * Nd, 0, 1, N, 64);
}

// Round 2
// 1020.385 us; speedup vs baseline: 1.2463x; 1.1215x over previous
//
#include <hip/hip_runtime.h>
#include <hip/hip_bf16.h>
#include <stdint.h>

static constexpr int N_NODES = 100000;
static constexpr int N_EDGES = 1600000;
static constexpr int PAD_ROWS = 100096;   // 782 * 128, removes GEMM A-tile bounds checks

// block-local partition CSR build: 512 rows per coarse bucket
static constexpr int CB_SHIFT = 9;
static constexpr int CRPB = 1 << CB_SHIFT;            // 512 rows / bucket
static constexpr int NCB = 196;                       // covers 100352 >= PAD_ROWS
static constexpr int CCAP = 8960;                     // mean 8192, sd 90 -> +8.5 sigma
static constexpr int CHUNK = 4096;                    // edges per partition block

typedef _Float16 f16;
using f16x8 = __attribute__((ext_vector_type(8))) _Float16;
using f16x4v = __attribute__((ext_vector_type(4))) _Float16;
using f32x4 = __attribute__((ext_vector_type(4))) float;

__device__ __forceinline__ void gld_lds16(const void* g, void* l) {
  __builtin_amdgcn_global_load_lds((const __attribute__((address_space(1))) void*)g,
                                   (__attribute__((address_space(3))) void*)l, 16, 0, 0);
}

// piecewise multi-term ReLU activation: 1.8*soft(0.1) - 0.8*soft(0.5)
__device__ __forceinline__ float custom_act(float x) {
  float s1 = fmaxf(x - 0.1f, 0.f) - fmaxf(-x - 0.1f, 0.f);
  float s2 = fmaxf(x - 0.5f, 0.f) - fmaxf(-x - 0.5f, 0.f);
  return 1.8f * s1 - 0.8f * s2;
}

// ---------------- conversions ----------------
__global__ __launch_bounds__(256) void xconv_k(const float* __restrict__ src, f16* __restrict__ dst, int n4) {
  int i = blockIdx.x * 256 + threadIdx.x;
  if (i < n4) {
    float4 v = ((const float4*)src)[i];
    f16x4v h = {(f16)v.x, (f16)v.y, (f16)v.z, (f16)v.w};
    ((f16x4v*)dst)[i] = h;
  }
}
// fp32 [K][N] -> f16 [N][K]
__global__ __launch_bounds__(256) void wconv_k(const float* __restrict__ src, f16* __restrict__ dst, int K, int N) {
  int i = blockIdx.x * 256 + threadIdx.x;
  if (i < K * N) { int k = i / N, n = i - k * N; dst[n * K + k] = (f16)src[i]; }
}

// ---------------- block-local partition (phase 1) ----------------
// Each block owns CHUNK contiguous edges. LDS histogram over coarse buckets,
// one global reservation per bucket per block, then scatter into the block's
// PRIVATE contiguous run inside each bucket region -> every 64B line of buf is
// filled by one block while L2-resident (no partial-line write amplification).
__global__ __launch_bounds__(256) void part_k(const int* __restrict__ Ai, const float* __restrict__ Av,
                                              int* __restrict__ bcA, int2* __restrict__ bufA,
                                              const int* __restrict__ Li, const float* __restrict__ Lv,
                                              int* __restrict__ bcL, int2* __restrict__ bufL, int E) {
  __shared__ int histA[NCB], histL[NCB];
  __shared__ int baseA[NCB], baseL[NCB];
  int tid = threadIdx.x;
  int e0 = blockIdx.x * CHUNK;
  int e1 = min(e0 + CHUNK, E);
  for (int i = tid; i < NCB; i += 256) { histA[i] = 0; histL[i] = 0; }
  __syncthreads();
  for (int e = e0 + tid; e < e1; e += 256) {
    atomicAdd(&histA[Ai[e] >> CB_SHIFT], 1);
    atomicAdd(&histL[Li[e] >> CB_SHIFT], 1);
  }
  __syncthreads();
  if (tid < NCB) {
    int hA = histA[tid], hL = histL[tid];
    baseA[tid] = hA ? atomicAdd(&bcA[tid * 16], hA) : 0;
    baseL[tid] = hL ? atomicAdd(&bcL[tid * 16], hL) : 0;
    histA[tid] = 0;
    histL[tid] = 0;
  }
  __syncthreads();
  for (int e = e0 + tid; e < e1; e += 256) {
    {
      int r = Ai[e], c = Ai[E + e];
      int b = r >> CB_SHIFT;
      int p = baseA[b] + atomicAdd(&histA[b], 1);
      if (p < CCAP) bufA[(size_t)b * CCAP + p] = make_int2(((r & (CRPB - 1)) << 17) | c, __float_as_int(Av[e]));
    }
    {
      int r = Li[e], c = Li[E + e];
      int b = r >> CB_SHIFT;
      int p = baseL[b] + atomicAdd(&histL[b], 1);
      if (p < CCAP) bufL[(size_t)b * CCAP + p] = make_int2(((r & (CRPB - 1)) << 17) | c, __float_as_int(Lv[e]));
    }
  }
}

// scan bucket totals (strided counters) -> bucket base offsets
__global__ __launch_bounds__(1024) void scan_k(const int* __restrict__ cntA, int* __restrict__ rpA,
                                               const int* __restrict__ cntL, int* __restrict__ rpL,
                                               int n, int stride) {
  const int* cnt = blockIdx.x ? cntL : cntA;
  int* rp = blockIdx.x ? rpL : rpA;
  __shared__ int wsum[16];
  __shared__ int carry_s;
  int tid = threadIdx.x, lane = tid & 63, wv = tid >> 6;
  if (tid == 0) carry_s = 0;
  __syncthreads();
  for (int base = 0; base < n; base += 1024) {
    int i = base + tid;
    int v = (i < n) ? cnt[i * stride] : 0;
    int s = v;
    #pragma unroll
    for (int off = 1; off < 64; off <<= 1) {
      int t = __shfl_up(s, off, 64);
      if (lane >= off) s += t;
    }
    if (lane == 63) wsum[wv] = s;
    __syncthreads();
    if (wv == 0 && lane < 16) {
      int w = wsum[lane];
      #pragma unroll
      for (int off = 1; off < 16; off <<= 1) {
        int t = __shfl_up(w, off, 64);
        if (lane >= off) w += t;
      }
      wsum[lane] = w;
    }
    __syncthreads();
    int carry = carry_s;
    int woff = wv ? wsum[wv - 1] : 0;
    if (i < n) rp[i] = carry + woff + s - v;
    __syncthreads();
    if (tid == 1023) carry_s = carry + woff + s;
    __syncthreads();
  }
  if (tid == 0) rp[n] = carry_s;
}

// ---------------- per-bucket ordering (phase 2) ----------------
// One block per (coarse bucket, matrix). Two passes over the bucket's records
// (second pass L2-hot): LDS row-histogram, 512-counter scan (2 per thread),
// coalesced rp slice write, scatter into the bucket's contiguous rec window.
__global__ __launch_bounds__(256) void place_k(const int* __restrict__ bcA, const int* __restrict__ bbA,
                                               const int2* __restrict__ bufA, int* __restrict__ rpA,
                                               int2* __restrict__ recA,
                                               const int* __restrict__ bcL, const int* __restrict__ bbL,
                                               const int2* __restrict__ bufL, int* __restrict__ rpL,
                                               int2* __restrict__ recL) {
  const int b = blockIdx.x;
  const int* bc; const int* bb; const int2* buf; int* rp; int2* rec;
  if (blockIdx.y) { bc = bcL; bb = bbL; buf = bufL; rp = rpL; rec = recL; }
  else            { bc = bcA; bb = bbA; buf = bufA; rp = rpA; rec = recA; }
  __shared__ int lcnt[CRPB];
  __shared__ int wsum[4];
  int tid = threadIdx.x, lane = tid & 63, wv = tid >> 6;
  int nrec = min(bc[b * 16], CCAP);
  const int2* src = buf + (size_t)b * CCAP;
  lcnt[2 * tid] = 0;
  lcnt[2 * tid + 1] = 0;
  __syncthreads();
  for (int i = tid; i < nrec; i += 256) atomicAdd(&lcnt[src[i].x >> 17], 1);
  __syncthreads();
  int c0 = lcnt[2 * tid], c1 = lcnt[2 * tid + 1];
  int s = c0 + c1;
  int incl = s;
  #pragma unroll
  for (int off = 1; off < 64; off <<= 1) {
    int t = __shfl_up(incl, off, 64);
    if (lane >= off) incl += t;
  }
  if (lane == 63) wsum[wv] = incl;
  __syncthreads();
  int woff = 0;
  for (int w = 0; w < wv; ++w) woff += wsum[w];
  int base0 = bb[b] + woff + incl - s;    // exclusive prefix + global bucket base
  int base1 = base0 + c0;
  __syncthreads();
  lcnt[2 * tid] = base0;
  lcnt[2 * tid + 1] = base1;
  rp[b * CRPB + 2 * tid] = base0;         // rows >= N get the running total (== E at tail)
  rp[b * CRPB + 2 * tid + 1] = base1;
  __syncthreads();
  for (int i = tid; i < nrec; i += 256) {
    int2 r = src[i];
    int pos = atomicAdd(&lcnt[r.x >> 17], 1);
    rec[pos] = make_int2(r.x & 0x1FFFF, r.y);
  }
}

// ---------------- gather SpMM over f16 features, fp32 accumulate ----------------
// mode 0: out = relu(acc + bias);  mode 1: out = custom_act(base - acc) (in-place ok)
template<int VEC>
__global__ __launch_bounds__(256) void spmm_k(const int* __restrict__ rp, const int2* __restrict__ rec,
                                              const f16* __restrict__ X,
                                              const f16* __restrict__ base, const float* __restrict__ bias,
                                              f16* __restrict__ out, int mode, int nrows) {
  int lane = threadIdx.x & 63;
  int row = blockIdx.x * 4 + (threadIdx.x >> 6);
  if (row >= nrows) return;
  const int M = VEC * 64;
  int p0 = rp[row], p1 = rp[row + 1];
  float acc[VEC] = {};
  int p = p0;
  for (; p + 1 < p1; p += 2) {
    int2 e0 = rec[p], e1 = rec[p + 1];
    float v0 = __int_as_float(e0.y), v1 = __int_as_float(e1.y);
    if (VEC == 4) {
      f16x4v x0 = *(const f16x4v*)(X + (size_t)e0.x * M + lane * 4);
      f16x4v x1 = *(const f16x4v*)(X + (size_t)e1.x * M + lane * 4);
      #pragma unroll
      for (int j = 0; j < 4; ++j) acc[j] += v0 * (float)x0[j] + v1 * (float)x1[j];
    } else {
      float x0 = (float)X[(size_t)e0.x * M + lane];
      float x1 = (float)X[(size_t)e1.x * M + lane];
      acc[0] += v0 * x0 + v1 * x1;
    }
  }
  if (p < p1) {
    int2 e0 = rec[p];
    float v0 = __int_as_float(e0.y);
    if (VEC == 4) {
      f16x4v x0 = *(const f16x4v*)(X + (size_t)e0.x * M + lane * 4);
      #pragma unroll
      for (int j = 0; j < 4; ++j) acc[j] += v0 * (float)x0[j];
    } else {
      acc[0] += v0 * (float)X[(size_t)e0.x * M + lane];
    }
  }
  size_t o = (size_t)row * M + (size_t)lane * VEC;
  if (VEC == 4) {
    f16x4v r;
    if (mode == 0) {
      #pragma unroll
      for (int j = 0; j < 4; ++j) r[j] = (f16)fmaxf(acc[j] + bias[lane * 4 + j], 0.f);
    } else {
      f16x4v bv = *(const f16x4v*)(base + o);
      #pragma unroll
      for (int j = 0; j < 4; ++j) r[j] = (f16)custom_act((float)bv[j] - acc[j]);
    }
    *(f16x4v*)(out + o) = r;
  } else {
    if (mode == 0) out[o] = (f16)fmaxf(acc[0] + bias[lane], 0.f);
    else out[o] = (f16)custom_act((float)base[o] - acc[0]);
  }
}

// ---------------- f16 MFMA GEMM with global_load_lds staging ----------------
// C = epi(A1@B1 [+ A2@B2] + bias). A row-major (PAD_ROWS rows allocated, no load
// bounds checks); Bt pre-transposed f16 [N][K]; tile 128 x BN, BK=32,
// 4 waves x 32 rows, mfma_f32_16x16x32_f16 (layouts as verified in round 4).
template<int BN>
__global__ __launch_bounds__(256) void gemm_k(const f16* __restrict__ A1, int K1,
                                              const f16* __restrict__ A2, int K2,
                                              const f16* __restrict__ B1t, const f16* __restrict__ B2t,
                                              const float* __restrict__ bias,
                                              void* __restrict__ C, int cf16, int epi,
                                              int nrows, int ldc) {
  __shared__ f16 As[128 * 32];
  __shared__ f16 Bs[BN * 32];
  int tid = threadIdx.x, lane = tid & 63, wv = tid >> 6;
  int m16 = lane & 15, quad = lane >> 4;
  int r0 = blockIdx.x * 128, c0 = blockIdx.y * BN;
  int wr0 = wv * 32;
  f32x4 acc[2][BN / 16] = {};
  // staging geometry: lane l stages row base+(l>>2), granule l&3 -> lds base + 16B*l
  int srow = lane >> 2, scol = (lane & 3) * 8;
  for (int src = 0; src < 2; ++src) {
    const f16* A = src ? A2 : A1;
    if (!A) continue;
    int K = src ? K2 : K1;
    const f16* Bt = src ? B2t : B1t;
    const f16* gA = A + (size_t)(r0 + wr0 + srow) * K + scol;
    const f16* gB = (BN == 128) ? Bt + (size_t)(c0 + wr0 + srow) * K + scol
                                : Bt + (size_t)(c0 + wv * 16 + srow) * K + scol;
    f16* lA = &As[wr0 * 32];
    f16* lB = (BN == 128) ? &Bs[wr0 * 32] : &Bs[wv * 16 * 32];
    for (int k0 = 0; k0 < K; k0 += 32) {
      gld_lds16(gA + k0, lA);
      gld_lds16(gA + k0 + (size_t)16 * K, lA + 512);
      gld_lds16(gB + k0, lB);
      if (BN == 128) gld_lds16(gB + k0 + (size_t)16 * K, lB + 512);
      __syncthreads();
      f16x8 a0 = *(const f16x8*)&As[(wr0 + m16) * 32 + quad * 8];
      f16x8 a1 = *(const f16x8*)&As[(wr0 + 16 + m16) * 32 + quad * 8];
      #pragma unroll
      for (int bt = 0; bt < BN / 16; ++bt) {
        f16x8 b = *(const f16x8*)&Bs[(bt * 16 + m16) * 32 + quad * 8];
        acc[0][bt] = __builtin_amdgcn_mfma_f32_16x16x32_f16(a0, b, acc[0][bt], 0, 0, 0);
        acc[1][bt] = __builtin_amdgcn_mfma_f32_16x16x32_f16(a1, b, acc[1][bt], 0, 0, 0);
      }
      __syncthreads();
    }
  }
  #pragma unroll
  for (int rt = 0; rt < 2; ++rt) {
    #pragma unroll
    for (int bt = 0; bt < BN / 16; ++bt) {
      #pragma unroll
      for (int j = 0; j < 4; ++j) {
        int row = r0 + wr0 + rt * 16 + quad * 4 + j;
        if (row >= nrows) continue;
        int colp = c0 + bt * 16 + m16;
        float v = acc[rt][bt][j];
        if (bias) v += bias[colp];
        if (epi == 1) v = tanhf(v);
        size_t o = (size_t)row * ldc + colp;
        if (cf16) ((f16*)C)[o] = (f16)v;
        else ((float*)C)[o] = v;
      }
    }
  }
}

extern "C" void kernel_launch(void* const* d_in, const int* in_sizes, int n_in,
                              void* d_out, int out_size, void* d_ws, size_t ws_size,
                              hipStream_t stream) {
  const float* x  = (const float*)d_in[0];
  const int*   Ai = (const int*)d_in[1];
  const float* Av = (const float*)d_in[2];
  const int*   Li = (const int*)d_in[3];
  const float* Lv = (const float*)d_in[4];
  const float* gcn_w0 = (const float*)d_in[5];
  const float* gcn_b0 = (const float*)d_in[6];
  const float* pai1_0 = (const float*)d_in[7];
  const float* pai2_0 = (const float*)d_in[8];
  const float* w1_w0  = (const float*)d_in[9];
  const float* w1_b0  = (const float*)d_in[10];
  const float* w2_w0  = (const float*)d_in[11];
  const float* w2_b0  = (const float*)d_in[12];
  const float* gcn_w1 = (const float*)d_in[13];
  const float* gcn_b1 = (const float*)d_in[14];
  const float* pai1_1 = (const float*)d_in[15];
  const float* pai2_1 = (const float*)d_in[16];
  const float* w1_w1  = (const float*)d_in[17];
  const float* w1_b1  = (const float*)d_in[18];
  const float* w2_w1  = (const float*)d_in[19];
  const float* w2_b1  = (const float*)d_in[20];
  float* out = (float*)d_out;

  const int N = N_NODES, E = N_EDGES;
  const size_t PH = (size_t)PAD_ROWS * 256;   // padded f16 elems per 256-wide matrix
  const size_t Pd = (size_t)PAD_ROWS * 64;
  const size_t Nd = (size_t)N * 64;

  // ---- workspace carve ----
  f16* xh  = (f16*)d_ws;               // PH
  f16* R1  = xh + PH;                  // PH
  f16* R2  = R1 + PH;                  // PH
  f16* wts = R2 + PH;                  // 274432 f16 weight pool
  f16* gcn_w0t = wts;
  f16* pai1_0t = gcn_w0t + 65536;
  f16* pai2_0t = pai1_0t + 65536;
  f16* w1_w0t  = pai2_0t + 65536;
  f16* w2_w0t  = w1_w0t + 16384;
  f16* gcn_w1t = w2_w0t + 16384;
  f16* pai2_1t = gcn_w1t + 16384;
  f16* pai1_1t = pai2_1t + 16384;
  f16* w1_w1t  = pai1_1t + 4096;
  f16* w2_w1t  = w1_w1t + 4096;
  int2* recA = (int2*)(((uintptr_t)(w2_w1t + 4096) + 255) & ~(uintptr_t)255);  // E
  int2* recL = recA + E;                                                        // E
  int*  rpA  = (int*)(recL + E);       // PAD_ROWS + 512 (place writes to 100351)
  int*  rpL  = rpA + (PAD_ROWS + 512);
  int*  bcA  = rpL + (PAD_ROWS + 512); // NCB*16 (padded counters)
  int*  bcL  = bcA + NCB * 16;         // NCB*16
  int*  bbA  = bcL + NCB * 16;         // NCB+1
  int*  bbL  = bbA + (NCB + 1);        // NCB+1

  // bucket buffers alias R1 (stream-ordered: CSR build completes before first GEMM writes R1)
  int2* bufA = (int2*)R1;                       // NCB*CCAP records (14 MB)
  int2* bufL = bufA + (size_t)NCB * CCAP;       // NCB*CCAP records (14 MB)

  // layer-1 sub-buffers inside R2 (ldc=64, padded rows)
  f16* T1h   = R2;
  f16* Ztp1h = R2 + Pd;
  f16* Z1bh  = R2 + 2 * Pd;

  // ---- conversions + CSR build ----
  xconv_k<<<(int)(((size_t)N * 64 + 255) / 256), 256, 0, stream>>>(x, xh, N * 64);
  wconv_k<<<(65536 + 255) / 256, 256, 0, stream>>>(gcn_w0, gcn_w0t, 256, 256);
  wconv_k<<<(65536 + 255) / 256, 256, 0, stream>>>(pai1_0, pai1_0t, 256, 256);
  wconv_k<<<(65536 + 255) / 256, 256, 0, stream>>>(pai2_0, pai2_0t, 256, 256);
  wconv_k<<<(16384 + 255) / 256, 256, 0, stream>>>(w1_w0, w1_w0t, 256, 64);
  wconv_k<<<(16384 + 255) / 256, 256, 0, stream>>>(w2_w0, w2_w0t, 256, 64);
  wconv_k<<<(16384 + 255) / 256, 256, 0, stream>>>(gcn_w1, gcn_w1t, 256, 64);
  wconv_k<<<(16384 + 255) / 256, 256, 0, stream>>>(pai2_1, pai2_1t, 256, 64);
  wconv_k<<<(4096 + 255) / 256, 256, 0, stream>>>(pai1_1, pai1_1t, 64, 64);
  wconv_k<<<(4096 + 255) / 256, 256, 0, stream>>>(w1_w1, w1_w1t, 64, 64);
  wconv_k<<<(4096 + 255) / 256, 256, 0, stream>>>(w2_w1, w2_w1t, 64, 64);

  hipMemsetAsync(bcA, 0, sizeof(int) * (size_t)NCB * 16 * 2, stream);
  part_k<<<(E + CHUNK - 1) / CHUNK, 256, 0, stream>>>(Ai, Av, bcA, bufA, Li, Lv, bcL, bufL, E);
  scan_k<<<2, 1024, 0, stream>>>(bcA, bbA, bcL, bbL, NCB, 16);
  place_k<<<dim3(NCB, 2), 256, 0, stream>>>(bcA, bbA, bufA, rpA, recA,
                                            bcL, bbL, bufL, rpL, recL);

  const int MB = PAD_ROWS / 128;  // 782
  dim3 g256(MB, 2), g64(MB, 1);
  const int spmm_grid = (N + 3) / 4;

  // ---- layer 0 ----
  gemm_k<128><<<g256, 256, 0, stream>>>(xh, 256, nullptr, 0, gcn_w0t, nullptr, nullptr, R1, 1, 0, N, 256);
  spmm_k<4><<<spmm_grid, 256, 0, stream>>>(rpA, recA, R1, nullptr, gcn_b0, R2, 0, N);
  gemm_k<64><<<g64, 256, 0, stream>>>(R2, 256, nullptr, 0, w1_w0t, nullptr, w1_b0, out, 0, 1, N, 64);
  gemm_k<128><<<g256, 256, 0, stream>>>(R2, 256, xh, 256, pai1_0t, pai2_0t, nullptr, R1, 1, 0, N, 256);
  spmm_k<4><<<spmm_grid, 256, 0, stream>>>(rpL, recL, R2, R1, nullptr, R1, 1, N);
  gemm_k<64><<<g64, 256, 0, stream>>>(R1, 256, nullptr, 0, w2_w0t, nullptr, w2_b0, out + 2 * Nd, 0, 1, N, 64);

  // ---- layer 1 ----
  gemm_k<64><<<g64, 256, 0, stream>>>(R1, 256, nullptr, 0, gcn_w1t, nullptr, nullptr, T1h, 1, 0, N, 64);
  spmm_k<1><<<spmm_grid, 256, 0, stream>>>(rpA, recA, T1h, nullptr, gcn_b1, Ztp1h, 0, N);
  gemm_k<64><<<g64, 256, 0, stream>>>(Ztp1h, 64, nullptr, 0, w1_w1t, nullptr, w1_b1, out + Nd, 0, 1, N, 64);
  gemm_k<64><<<g64, 256, 0, stream>>>(Ztp1h, 64, xh, 256, pai1_1t, pai2_1t, nullptr, Z1bh, 1, 0, N, 64);
  spmm_k<1><<<spmm_grid, 256, 0, stream>>>(rpL, recL, Ztp1h, Z1bh, nullptr, Z1bh, 1, N);
  gemm_k<64><<<g64, 256, 0, stream>>>(Z1bh, 64, nullptr, 0, w2_w1t, nullptr, w2_b1, out + 3 * Nd, 0, 1, N, 64);
}

// Round 3
// 898.018 us; speedup vs baseline: 1.4161x; 1.1363x over previous
//
#include <hip/hip_runtime.h>
#include <hip/hip_bf16.h>
#include <stdint.h>

static constexpr int N_NODES = 100000;
static constexpr int N_EDGES = 1600000;
static constexpr int PAD_ROWS = 100096;   // 782 * 128, removes GEMM A-tile bounds checks

// block-local partition CSR build: 512 rows per coarse bucket
static constexpr int CB_SHIFT = 9;
static constexpr int CRPB = 1 << CB_SHIFT;            // 512 rows / bucket
static constexpr int NCB = 196;                       // covers 100352 >= PAD_ROWS
static constexpr int CCAP = 8960;                     // mean 8192, sd 90 -> +8.5 sigma
static constexpr int CHUNK = 4096;                    // edges per partition block

typedef _Float16 f16;
using f16x8 = __attribute__((ext_vector_type(8))) _Float16;
using f16x4v = __attribute__((ext_vector_type(4))) _Float16;
using f32x4 = __attribute__((ext_vector_type(4))) float;

__device__ __forceinline__ void gld_lds16(const void* g, void* l) {
  __builtin_amdgcn_global_load_lds((const __attribute__((address_space(1))) void*)g,
                                   (__attribute__((address_space(3))) void*)l, 16, 0, 0);
}

// piecewise multi-term ReLU activation: 1.8*soft(0.1) - 0.8*soft(0.5)
__device__ __forceinline__ float custom_act(float x) {
  float s1 = fmaxf(x - 0.1f, 0.f) - fmaxf(-x - 0.1f, 0.f);
  float s2 = fmaxf(x - 0.5f, 0.f) - fmaxf(-x - 0.5f, 0.f);
  return 1.8f * s1 - 0.8f * s2;
}

// ---------------- conversions ----------------
__global__ __launch_bounds__(256) void xconv_k(const float* __restrict__ src, f16* __restrict__ dst, int n4) {
  int i = blockIdx.x * 256 + threadIdx.x;
  if (i < n4) {
    float4 v = ((const float4*)src)[i];
    f16x4v h = {(f16)v.x, (f16)v.y, (f16)v.z, (f16)v.w};
    ((f16x4v*)dst)[i] = h;
  }
}
// fp32 [K][N] -> f16 [N][K]
__global__ __launch_bounds__(256) void wconv_k(const float* __restrict__ src, f16* __restrict__ dst, int K, int N) {
  int i = blockIdx.x * 256 + threadIdx.x;
  if (i < K * N) { int k = i / N, n = i - k * N; dst[n * K + k] = (f16)src[i]; }
}

// ---------------- block-local partition (phase 1) ----------------
// Each block owns CHUNK contiguous edges. LDS histogram over coarse buckets,
// one global reservation per bucket per block, then scatter into the block's
// PRIVATE contiguous run inside each bucket region -> every 64B line of buf is
// filled by one block while L2-resident (no partial-line write amplification).
__global__ __launch_bounds__(256) void part_k(const int* __restrict__ Ai, const float* __restrict__ Av,
                                              int* __restrict__ bcA, int2* __restrict__ bufA,
                                              const int* __restrict__ Li, const float* __restrict__ Lv,
                                              int* __restrict__ bcL, int2* __restrict__ bufL, int E) {
  __shared__ int histA[NCB], histL[NCB];
  __shared__ int baseA[NCB], baseL[NCB];
  int tid = threadIdx.x;
  int e0 = blockIdx.x * CHUNK;
  int e1 = min(e0 + CHUNK, E);
  for (int i = tid; i < NCB; i += 256) { histA[i] = 0; histL[i] = 0; }
  __syncthreads();
  for (int e = e0 + tid; e < e1; e += 256) {
    atomicAdd(&histA[Ai[e] >> CB_SHIFT], 1);
    atomicAdd(&histL[Li[e] >> CB_SHIFT], 1);
  }
  __syncthreads();
  if (tid < NCB) {
    int hA = histA[tid], hL = histL[tid];
    baseA[tid] = hA ? atomicAdd(&bcA[tid * 16], hA) : 0;
    baseL[tid] = hL ? atomicAdd(&bcL[tid * 16], hL) : 0;
    histA[tid] = 0;
    histL[tid] = 0;
  }
  __syncthreads();
  for (int e = e0 + tid; e < e1; e += 256) {
    {
      int r = Ai[e], c = Ai[E + e];
      int b = r >> CB_SHIFT;
      int p = baseA[b] + atomicAdd(&histA[b], 1);
      if (p < CCAP) bufA[(size_t)b * CCAP + p] = make_int2(((r & (CRPB - 1)) << 17) | c, __float_as_int(Av[e]));
    }
    {
      int r = Li[e], c = Li[E + e];
      int b = r >> CB_SHIFT;
      int p = baseL[b] + atomicAdd(&histL[b], 1);
      if (p < CCAP) bufL[(size_t)b * CCAP + p] = make_int2(((r & (CRPB - 1)) << 17) | c, __float_as_int(Lv[e]));
    }
  }
}

// scan bucket totals (strided counters) -> bucket base offsets
__global__ __launch_bounds__(1024) void scan_k(const int* __restrict__ cntA, int* __restrict__ rpA,
                                               const int* __restrict__ cntL, int* __restrict__ rpL,
                                               int n, int stride) {
  const int* cnt = blockIdx.x ? cntL : cntA;
  int* rp = blockIdx.x ? rpL : rpA;
  __shared__ int wsum[16];
  __shared__ int carry_s;
  int tid = threadIdx.x, lane = tid & 63, wv = tid >> 6;
  if (tid == 0) carry_s = 0;
  __syncthreads();
  for (int base = 0; base < n; base += 1024) {
    int i = base + tid;
    int v = (i < n) ? cnt[i * stride] : 0;
    int s = v;
    #pragma unroll
    for (int off = 1; off < 64; off <<= 1) {
      int t = __shfl_up(s, off, 64);
      if (lane >= off) s += t;
    }
    if (lane == 63) wsum[wv] = s;
    __syncthreads();
    if (wv == 0 && lane < 16) {
      int w = wsum[lane];
      #pragma unroll
      for (int off = 1; off < 16; off <<= 1) {
        int t = __shfl_up(w, off, 64);
        if (lane >= off) w += t;
      }
      wsum[lane] = w;
    }
    __syncthreads();
    int carry = carry_s;
    int woff = wv ? wsum[wv - 1] : 0;
    if (i < n) rp[i] = carry + woff + s - v;
    __syncthreads();
    if (tid == 1023) carry_s = carry + woff + s;
    __syncthreads();
  }
  if (tid == 0) rp[n] = carry_s;
}

// ---------------- per-bucket ordering (phase 2) ----------------
// One block per (coarse bucket, matrix). Two passes over the bucket's records
// (second pass L2-hot): LDS row-histogram, 512-counter scan (2 per thread),
// coalesced rp slice write, scatter into the bucket's contiguous rec window.
__global__ __launch_bounds__(256) void place_k(const int* __restrict__ bcA, const int* __restrict__ bbA,
                                               const int2* __restrict__ bufA, int* __restrict__ rpA,
                                               int2* __restrict__ recA,
                                               const int* __restrict__ bcL, const int* __restrict__ bbL,
                                               const int2* __restrict__ bufL, int* __restrict__ rpL,
                                               int2* __restrict__ recL) {
  const int b = blockIdx.x;
  const int* bc; const int* bb; const int2* buf; int* rp; int2* rec;
  if (blockIdx.y) { bc = bcL; bb = bbL; buf = bufL; rp = rpL; rec = recL; }
  else            { bc = bcA; bb = bbA; buf = bufA; rp = rpA; rec = recA; }
  __shared__ int lcnt[CRPB];
  __shared__ int wsum[4];
  int tid = threadIdx.x, lane = tid & 63, wv = tid >> 6;
  int nrec = min(bc[b * 16], CCAP);
  const int2* src = buf + (size_t)b * CCAP;
  lcnt[2 * tid] = 0;
  lcnt[2 * tid + 1] = 0;
  __syncthreads();
  for (int i = tid; i < nrec; i += 256) atomicAdd(&lcnt[src[i].x >> 17], 1);
  __syncthreads();
  int c0 = lcnt[2 * tid], c1 = lcnt[2 * tid + 1];
  int s = c0 + c1;
  int incl = s;
  #pragma unroll
  for (int off = 1; off < 64; off <<= 1) {
    int t = __shfl_up(incl, off, 64);
    if (lane >= off) incl += t;
  }
  if (lane == 63) wsum[wv] = incl;
  __syncthreads();
  int woff = 0;
  for (int w = 0; w < wv; ++w) woff += wsum[w];
  int base0 = bb[b] + woff + incl - s;    // exclusive prefix + global bucket base
  int base1 = base0 + c0;
  __syncthreads();
  lcnt[2 * tid] = base0;
  lcnt[2 * tid + 1] = base1;
  rp[b * CRPB + 2 * tid] = base0;         // rows >= N get the running total (== E at tail)
  rp[b * CRPB + 2 * tid + 1] = base1;
  __syncthreads();
  for (int i = tid; i < nrec; i += 256) {
    int2 r = src[i];
    int pos = atomicAdd(&lcnt[r.x >> 17], 1);
    rec[pos] = make_int2(r.x & 0x1FFFF, r.y);
  }
}

// ---------------- gather SpMM over f16 features, fp32 accumulate ----------------
// mode 0: out = relu(acc + bias);  mode 1: out = custom_act(base - acc) (in-place ok)
// One wave per row. p0/p1 forced to SGPR via readfirstlane -> record loads are
// scalar; X gathers unrolled 8-deep for memory-level parallelism (LLC latency).
template<int VEC>
__global__ __launch_bounds__(256) void spmm_k(const int* __restrict__ rp, const int2* __restrict__ rec,
                                              const f16* __restrict__ X,
                                              const f16* __restrict__ base, const float* __restrict__ bias,
                                              f16* __restrict__ out, int mode, int nrows) {
  int lane = threadIdx.x & 63;
  int row = blockIdx.x * 4 + (threadIdx.x >> 6);
  if (row >= nrows) return;
  const int M = VEC * 64;
  int p0 = __builtin_amdgcn_readfirstlane(rp[row]);
  int p1 = __builtin_amdgcn_readfirstlane(rp[row + 1]);
  float acc[VEC] = {};
  int p = p0;
  for (; p + 7 < p1; p += 8) {
    int2 e[8];
    #pragma unroll
    for (int u = 0; u < 8; ++u) e[u] = rec[p + u];
    if (VEC == 4) {
      f16x4v xv[8];
      #pragma unroll
      for (int u = 0; u < 8; ++u) xv[u] = *(const f16x4v*)(X + (size_t)e[u].x * M + lane * 4);
      #pragma unroll
      for (int u = 0; u < 8; ++u) {
        float v = __int_as_float(e[u].y);
        #pragma unroll
        for (int j = 0; j < 4; ++j) acc[j] += v * (float)xv[u][j];
      }
    } else {
      float xv[8];
      #pragma unroll
      for (int u = 0; u < 8; ++u) xv[u] = (float)X[(size_t)e[u].x * M + lane];
      #pragma unroll
      for (int u = 0; u < 8; ++u) acc[0] += __int_as_float(e[u].y) * xv[u];
    }
  }
  for (; p + 1 < p1; p += 2) {
    int2 e0 = rec[p], e1 = rec[p + 1];
    float v0 = __int_as_float(e0.y), v1 = __int_as_float(e1.y);
    if (VEC == 4) {
      f16x4v x0 = *(const f16x4v*)(X + (size_t)e0.x * M + lane * 4);
      f16x4v x1 = *(const f16x4v*)(X + (size_t)e1.x * M + lane * 4);
      #pragma unroll
      for (int j = 0; j < 4; ++j) acc[j] += v0 * (float)x0[j] + v1 * (float)x1[j];
    } else {
      float x0 = (float)X[(size_t)e0.x * M + lane];
      float x1 = (float)X[(size_t)e1.x * M + lane];
      acc[0] += v0 * x0 + v1 * x1;
    }
  }
  if (p < p1) {
    int2 e0 = rec[p];
    float v0 = __int_as_float(e0.y);
    if (VEC == 4) {
      f16x4v x0 = *(const f16x4v*)(X + (size_t)e0.x * M + lane * 4);
      #pragma unroll
      for (int j = 0; j < 4; ++j) acc[j] += v0 * (float)x0[j];
    } else {
      acc[0] += v0 * (float)X[(size_t)e0.x * M + lane];
    }
  }
  size_t o = (size_t)row * M + (size_t)lane * VEC;
  if (VEC == 4) {
    f16x4v r;
    if (mode == 0) {
      #pragma unroll
      for (int j = 0; j < 4; ++j) r[j] = (f16)fmaxf(acc[j] + bias[lane * 4 + j], 0.f);
    } else {
      f16x4v bv = *(const f16x4v*)(base + o);
      #pragma unroll
      for (int j = 0; j < 4; ++j) r[j] = (f16)custom_act((float)bv[j] - acc[j]);
    }
    *(f16x4v*)(out + o) = r;
  } else {
    if (mode == 0) out[o] = (f16)fmaxf(acc[0] + bias[lane], 0.f);
    else out[o] = (f16)custom_act((float)base[o] - acc[0]);
  }
}

// ---------------- f16 MFMA GEMM with global_load_lds staging ----------------
// C = epi(A1@B1 [+ A2@B2] + bias). A row-major (PAD_ROWS rows allocated, no load
// bounds checks); Bt pre-transposed f16 [N][K]; tile 128 x BN, BK=32,
// 4 waves x 32 rows, mfma_f32_16x16x32_f16 (layouts as verified in round 4).
template<int BN>
__global__ __launch_bounds__(256) void gemm_k(const f16* __restrict__ A1, int K1,
                                              const f16* __restrict__ A2, int K2,
                                              const f16* __restrict__ B1t, const f16* __restrict__ B2t,
                                              const float* __restrict__ bias,
                                              void* __restrict__ C, int cf16, int epi,
                                              int nrows, int ldc) {
  __shared__ f16 As[128 * 32];
  __shared__ f16 Bs[BN * 32];
  int tid = threadIdx.x, lane = tid & 63, wv = tid >> 6;
  int m16 = lane & 15, quad = lane >> 4;
  int r0 = blockIdx.x * 128, c0 = blockIdx.y * BN;
  int wr0 = wv * 32;
  f32x4 acc[2][BN / 16] = {};
  // staging geometry: lane l stages row base+(l>>2), granule l&3 -> lds base + 16B*l
  int srow = lane >> 2, scol = (lane & 3) * 8;
  for (int src = 0; src < 2; ++src) {
    const f16* A = src ? A2 : A1;
    if (!A) continue;
    int K = src ? K2 : K1;
    const f16* Bt = src ? B2t : B1t;
    const f16* gA = A + (size_t)(r0 + wr0 + srow) * K + scol;
    const f16* gB = (BN == 128) ? Bt + (size_t)(c0 + wr0 + srow) * K + scol
                                : Bt + (size_t)(c0 + wv * 16 + srow) * K + scol;
    f16* lA = &As[wr0 * 32];
    f16* lB = (BN == 128) ? &Bs[wr0 * 32] : &Bs[wv * 16 * 32];
    for (int k0 = 0; k0 < K; k0 += 32) {
      gld_lds16(gA + k0, lA);
      gld_lds16(gA + k0 + (size_t)16 * K, lA + 512);
      gld_lds16(gB + k0, lB);
      if (BN == 128) gld_lds16(gB + k0 + (size_t)16 * K, lB + 512);
      __syncthreads();
      f16x8 a0 = *(const f16x8*)&As[(wr0 + m16) * 32 + quad * 8];
      f16x8 a1 = *(const f16x8*)&As[(wr0 + 16 + m16) * 32 + quad * 8];
      #pragma unroll
      for (int bt = 0; bt < BN / 16; ++bt) {
        f16x8 b = *(const f16x8*)&Bs[(bt * 16 + m16) * 32 + quad * 8];
        acc[0][bt] = __builtin_amdgcn_mfma_f32_16x16x32_f16(a0, b, acc[0][bt], 0, 0, 0);
        acc[1][bt] = __builtin_amdgcn_mfma_f32_16x16x32_f16(a1, b, acc[1][bt], 0, 0, 0);
      }
      __syncthreads();
    }
  }
  #pragma unroll
  for (int rt = 0; rt < 2; ++rt) {
    #pragma unroll
    for (int bt = 0; bt < BN / 16; ++bt) {
      #pragma unroll
      for (int j = 0; j < 4; ++j) {
        int row = r0 + wr0 + rt * 16 + quad * 4 + j;
        if (row >= nrows) continue;
        int colp = c0 + bt * 16 + m16;
        float v = acc[rt][bt][j];
        if (bias) v += bias[colp];
        if (epi == 1) v = tanhf(v);
        size_t o = (size_t)row * ldc + colp;
        if (cf16) ((f16*)C)[o] = (f16)v;
        else ((float*)C)[o] = v;
      }
    }
  }
}

extern "C" void kernel_launch(void* const* d_in, const int* in_sizes, int n_in,
                              void* d_out, int out_size, void* d_ws, size_t ws_size,
                              hipStream_t stream) {
  const float* x  = (const float*)d_in[0];
  const int*   Ai = (const int*)d_in[1];
  const float* Av = (const float*)d_in[2];
  const int*   Li = (const int*)d_in[3];
  const float* Lv = (const float*)d_in[4];
  const float* gcn_w0 = (const float*)d_in[5];
  const float* gcn_b0 = (const float*)d_in[6];
  const float* pai1_0 = (const float*)d_in[7];
  const float* pai2_0 = (const float*)d_in[8];
  const float* w1_w0  = (const float*)d_in[9];
  const float* w1_b0  = (const float*)d_in[10];
  const float* w2_w0  = (const float*)d_in[11];
  const float* w2_b0  = (const float*)d_in[12];
  const float* gcn_w1 = (const float*)d_in[13];
  const float* gcn_b1 = (const float*)d_in[14];
  const float* pai1_1 = (const float*)d_in[15];
  const float* pai2_1 = (const float*)d_in[16];
  const float* w1_w1  = (const float*)d_in[17];
  const float* w1_b1  = (const float*)d_in[18];
  const float* w2_w1  = (const float*)d_in[19];
  const float* w2_b1  = (const float*)d_in[20];
  float* out = (float*)d_out;

  const int N = N_NODES, E = N_EDGES;
  const size_t PH = (size_t)PAD_ROWS * 256;   // padded f16 elems per 256-wide matrix
  const size_t Pd = (size_t)PAD_ROWS * 64;
  const size_t Nd = (size_t)N * 64;

  // ---- workspace carve ----
  f16* xh  = (f16*)d_ws;               // PH
  f16* R1  = xh + PH;                  // PH
  f16* R2  = R1 + PH;                  // PH
  f16* wts = R2 + PH;                  // 274432 f16 weight pool
  f16* gcn_w0t = wts;
  f16* pai1_0t = gcn_w0t + 65536;
  f16* pai2_0t = pai1_0t + 65536;
  f16* w1_w0t  = pai2_0t + 65536;
  f16* w2_w0t  = w1_w0t + 16384;
  f16* gcn_w1t = w2_w0t + 16384;
  f16* pai2_1t = gcn_w1t + 16384;
  f16* pai1_1t = pai2_1t + 16384;
  f16* w1_w1t  = pai1_1t + 4096;
  f16* w2_w1t  = w1_w1t + 4096;
  int2* recA = (int2*)(((uintptr_t)(w2_w1t + 4096) + 255) & ~(uintptr_t)255);  // E
  int2* recL = recA + E;                                                        // E
  int*  rpA  = (int*)(recL + E);       // PAD_ROWS + 512 (place writes to 100351)
  int*  rpL  = rpA + (PAD_ROWS + 512);
  int*  bcA  = rpL + (PAD_ROWS + 512); // NCB*16 (padded counters)
  int*  bcL  = bcA + NCB * 16;         // NCB*16
  int*  bbA  = bcL + NCB * 16;         // NCB+1
  int*  bbL  = bbA + (NCB + 1);        // NCB+1

  // bucket buffers alias R1 (stream-ordered: CSR build completes before first GEMM writes R1)
  int2* bufA = (int2*)R1;                       // NCB*CCAP records (14 MB)
  int2* bufL = bufA + (size_t)NCB * CCAP;       // NCB*CCAP records (14 MB)

  // layer-1 sub-buffers inside R2 (ldc=64, padded rows)
  f16* T1h   = R2;
  f16* Ztp1h = R2 + Pd;
  f16* Z1bh  = R2 + 2 * Pd;

  // ---- conversions + CSR build ----
  xconv_k<<<(int)(((size_t)N * 64 + 255) / 256), 256, 0, stream>>>(x, xh, N * 64);
  wconv_k<<<(65536 + 255) / 256, 256, 0, stream>>>(gcn_w0, gcn_w0t, 256, 256);
  wconv_k<<<(65536 + 255) / 256, 256, 0, stream>>>(pai1_0, pai1_0t, 256, 256);
  wconv_k<<<(65536 + 255) / 256, 256, 0, stream>>>(pai2_0, pai2_0t, 256, 256);
  wconv_k<<<(16384 + 255) / 256, 256, 0, stream>>>(w1_w0, w1_w0t, 256, 64);
  wconv_k<<<(16384 + 255) / 256, 256, 0, stream>>>(w2_w0, w2_w0t, 256, 64);
  wconv_k<<<(16384 + 255) / 256, 256, 0, stream>>>(gcn_w1, gcn_w1t, 256, 64);
  wconv_k<<<(16384 + 255) / 256, 256, 0, stream>>>(pai2_1, pai2_1t, 256, 64);
  wconv_k<<<(4096 + 255) / 256, 256, 0, stream>>>(pai1_1, pai1_1t, 64, 64);
  wconv_k<<<(4096 + 255) / 256, 256, 0, stream>>>(w1_w1, w1_w1t, 64, 64);
  wconv_k<<<(4096 + 255) / 256, 256, 0, stream>>>(w2_w1, w2_w1t, 64, 64);

  hipMemsetAsync(bcA, 0, sizeof(int) * (size_t)NCB * 16 * 2, stream);
  part_k<<<(E + CHUNK - 1) / CHUNK, 256, 0, stream>>>(Ai, Av, bcA, bufA, Li, Lv, bcL, bufL, E);
  scan_k<<<2, 1024, 0, stream>>>(bcA, bbA, bcL, bbL, NCB, 16);
  place_k<<<dim3(NCB, 2), 256, 0, stream>>>(bcA, bbA, bufA, rpA, recA,
                                            bcL, bbL, bufL, rpL, recL);

  const int MB = PAD_ROWS / 128;  // 782
  dim3 g256(MB, 2), g64(MB, 1);
  const int spmm_grid = (N + 3) / 4;

  // ---- layer 0 ----
  gemm_k<128><<<g256, 256, 0, stream>>>(xh, 256, nullptr, 0, gcn_w0t, nullptr, nullptr, R1, 1, 0, N, 256);
  spmm_k<4><<<spmm_grid, 256, 0, stream>>>(rpA, recA, R1, nullptr, gcn_b0, R2, 0, N);
  gemm_k<64><<<g64, 256, 0, stream>>>(R2, 256, nullptr, 0, w1_w0t, nullptr, w1_b0, out, 0, 1, N, 64);
  gemm_k<128><<<g256, 256, 0, stream>>>(R2, 256, xh, 256, pai1_0t, pai2_0t, nullptr, R1, 1, 0, N, 256);
  spmm_k<4><<<spmm_grid, 256, 0, stream>>>(rpL, recL, R2, R1, nullptr, R1, 1, N);
  gemm_k<64><<<g64, 256, 0, stream>>>(R1, 256, nullptr, 0, w2_w0t, nullptr, w2_b0, out + 2 * Nd, 0, 1, N, 64);

  // ---- layer 1 ----
  gemm_k<64><<<g64, 256, 0, stream>>>(R1, 256, nullptr, 0, gcn_w1t, nullptr, nullptr, T1h, 1, 0, N, 64);
  spmm_k<1><<<spmm_grid, 256, 0, stream>>>(rpA, recA, T1h, nullptr, gcn_b1, Ztp1h, 0, N);
  gemm_k<64><<<g64, 256, 0, stream>>>(Ztp1h, 64, nullptr, 0, w1_w1t, nullptr, w1_b1, out + Nd, 0, 1, N, 64);
  gemm_k<64><<<g64, 256, 0, stream>>>(Ztp1h, 64, xh, 256, pai1_1t, pai2_1t, nullptr, Z1bh, 1, 0, N, 64);
  spmm_k<1><<<spmm_grid, 256, 0, stream>>>(rpL, recL, Ztp1h, Z1bh, nullptr, Z1bh, 1, N);
  gemm_k<64><<<g64, 256, 0, stream>>>(Z1bh, 64, nullptr, 0, w2_w1t, nullptr, w2_b1, out + 3 * Nd, 0, 1, N, 64);
}